// Round 1
// 309.865 us; speedup vs baseline: 1.0854x; 1.0854x over previous
//
#include <hip/hip_runtime.h>
#include <stdint.h>

#define NEXP 8
#define DD   512
#define BM   64
#define BN   512

typedef short s16x8 __attribute__((ext_vector_type(8)));
typedef float f32x4 __attribute__((ext_vector_type(4)));

static __device__ __forceinline__ unsigned short f2bf(float f) {
    union { float f; unsigned u; } v; v.f = f;
    unsigned r = v.u + 0x7FFFu + ((v.u >> 16) & 1u);   // round-to-nearest-even
    return (unsigned short)(r >> 16);
}

// ---------------- bucketing kernels ----------------

__global__ void hist_kernel(const int* __restrict__ z, int* __restrict__ counts, int T) {
    __shared__ int lc[NEXP];
    int tid = threadIdx.x;
    if (tid < NEXP) lc[tid] = 0;
    __syncthreads();
    int t = blockIdx.x * blockDim.x + tid;
    if (t < T) atomicAdd(&lc[z[t]], 1);
    __syncthreads();
    if (tid < NEXP) atomicAdd(&counts[tid], lc[tid]);
}

__global__ void scan_kernel(const int* __restrict__ counts, int* __restrict__ cursors,
                            int4* __restrict__ table, int max_tiles) {
    __shared__ int off[NEXP + 1];
    __shared__ int tb[NEXP + 1];
    int tid = threadIdx.x;
    if (tid == 0) {
        int o = 0, tbs = 0;
        for (int e = 0; e < NEXP; e++) {
            off[e] = o; tb[e] = tbs;
            cursors[e] = o;
            int c = counts[e];
            o += c;
            tbs += (c + BM - 1) / BM;
        }
        off[NEXP] = o; tb[NEXP] = tbs;
    }
    __syncthreads();
    for (int idx = tid; idx < max_tiles; idx += blockDim.x) {
        int4 ent; ent.x = -1; ent.y = 0; ent.z = 0; ent.w = 0;
#pragma unroll
        for (int e = 0; e < NEXP; e++) {
            if (idx >= tb[e] && idx < tb[e + 1]) {
                int r = (idx - tb[e]) * BM;
                ent.x = e; ent.y = off[e] + r; ent.z = (off[e + 1] - off[e]) - r;
            }
        }
        table[idx] = ent;
    }
}

__global__ void scatter_kernel(const int* __restrict__ z, int* __restrict__ cursors,
                               int* __restrict__ token_index, float* __restrict__ zout, int T) {
    __shared__ int lc[NEXP];
    __shared__ int lbase[NEXP];
    int tid = threadIdx.x;
    if (tid < NEXP) lc[tid] = 0;
    __syncthreads();
    int t = blockIdx.x * blockDim.x + tid;
    int e = 0, rank = 0;
    if (t < T) {
        e = z[t];
        rank = atomicAdd(&lc[e], 1);
        zout[t] = (float)e;            // output 0: z as float
    }
    __syncthreads();
    if (tid < NEXP) lbase[tid] = atomicAdd(&cursors[tid], lc[tid]);
    __syncthreads();
    if (t < T) token_index[lbase[e] + rank] = t;
}

// W [8][k=512][n=512] f32  ->  Wt [8][n=512][k=512] bf16 (transposed, contiguous-k rows)
__global__ void convw_kernel(const float* __restrict__ W, unsigned short* __restrict__ Wt) {
    __shared__ float tile[32][33];
    int e = blockIdx.z, k0 = blockIdx.x * 32, n0 = blockIdx.y * 32;
    int tid = threadIdx.x;
    const float* We = W + (size_t)e * DD * DD;
    unsigned short* WtE = Wt + (size_t)e * DD * DD;
    int c = tid & 31, r0 = tid >> 5;
#pragma unroll
    for (int i = 0; i < 4; i++) {
        int kr = r0 + 8 * i;
        tile[kr][c] = We[(size_t)(k0 + kr) * DD + n0 + c];
    }
    __syncthreads();
#pragma unroll
    for (int i = 0; i < 4; i++) {
        int nr = r0 + 8 * i;
        WtE[(size_t)(n0 + nr) * DD + k0 + c] = f2bf(tile[c][nr]);
    }
}

// ---------------- fused grouped GEMM ----------------
// BM=64 rows x BN=512 (full width) per block: every x-row is fetched from HBM
// exactly once (no xg staging buffer, no N-dimension re-reads).
// A: f32 gathered rows -> in-register bf16 convert -> swizzled ds_write_b128.
// B: Wt bf16 via global_load_lds with pre-swizzled global source (chunk ^ (row&7)),
//    LDS linear dest -> ds_read_b128 fragments are 2-way (free) bank access.
// 512 threads, 72 KB LDS -> 2 blocks/CU for inter-block stage/MFMA overlap.

__global__ __launch_bounds__(512, 4) void gemm3_kernel(
    const float* __restrict__ x,
    const unsigned short* __restrict__ Wt,      // [8][n][k] bf16
    const float* __restrict__ bias,             // [8][512] f32
    const int* __restrict__ token_index,
    const int4* __restrict__ table,
    float* __restrict__ y)                      // [T][512] f32
{
    int4 te = table[blockIdx.x];
    const int e = te.x;
    if (e < 0) return;
    const int base = te.y;
    const int rows_valid = te.z < BM ? te.z : BM;

    __shared__ unsigned short Als[BM * 64];     // 8 KB
    __shared__ unsigned short Bls[BN * 64];     // 64 KB

    const int tid  = threadIdx.x;
    const int lane = tid & 63;
    const int wave = tid >> 6;                  // 0..7
    const int wn   = wave * 64;                 // per-wave N offset

    // staging geometry: one 16B chunk per thread for A, 8 for B
    const int ra  = tid >> 3;                   // 0..63 (row)
    const int ca  = tid & 7;                    // chunk slot in LDS
    const int gca = ca ^ (ra & 7);              // global chunk (XOR swizzle)

    const int rr  = (ra < rows_valid) ? ra : 0;
    const int tok = token_index[base + rr];
    const float* asrc = x + (size_t)tok * DD + gca * 8;

    const unsigned short* WtE  = Wt + (size_t)e * DD * DD;
    const unsigned short* bsrc = WtE + (size_t)ra * DD + gca * 8;

    f32x4 acc[4][4];
#pragma unroll
    for (int i = 0; i < 4; i++)
#pragma unroll
        for (int j = 0; j < 4; j++) acc[i][j] = (f32x4){0.f, 0.f, 0.f, 0.f};

    const int quad = lane >> 4;
    const int lrow = lane & 15;

    // prologue: A registers for k0 = 0
    float4 av0 = *(const float4*)(asrc);
    float4 av1 = *(const float4*)(asrc + 4);

    for (int k0 = 0; k0 < DD; k0 += 64) {
        __syncthreads();
        // A: convert current regs -> swizzled LDS slot (linear addr tid*16B)
        uint4 p;
        p.x = (unsigned)f2bf(av0.x) | ((unsigned)f2bf(av0.y) << 16);
        p.y = (unsigned)f2bf(av0.z) | ((unsigned)f2bf(av0.w) << 16);
        p.z = (unsigned)f2bf(av1.x) | ((unsigned)f2bf(av1.y) << 16);
        p.w = (unsigned)f2bf(av1.z) | ((unsigned)f2bf(av1.w) << 16);
        *(uint4*)(&Als[tid * 8]) = p;
        // B: 8 direct-to-LDS 16B loads per thread (rows ra, ra+64, ..., ra+448)
#pragma unroll
        for (int j = 0; j < 8; j++) {
            const unsigned short* gb = bsrc + (size_t)j * 64 * DD + k0;
            unsigned short* lb = &Bls[(size_t)(tid + j * 512) * 8];
            __builtin_amdgcn_global_load_lds((const __attribute__((address_space(1))) void*)gb,
                                             (__attribute__((address_space(3))) void*)lb, 16, 0, 0);
        }
        // prefetch next A chunk; latency rides with the B drain + next MFMA window
        if (k0 + 64 < DD) {
            av0 = *(const float4*)(asrc + k0 + 64);
            av1 = *(const float4*)(asrc + k0 + 68);
        }
        __syncthreads();

#pragma unroll
        for (int ks = 0; ks < 2; ks++) {
            s16x8 af[4], bq[4];
#pragma unroll
            for (int i = 0; i < 4; i++) {
                int r = i * 16 + lrow;
                af[i] = *(const s16x8*)(&Als[r * 64 + (((quad + 4 * ks) ^ (r & 7)) * 8)]);
            }
#pragma unroll
            for (int j = 0; j < 4; j++) {
                int n = wn + j * 16 + lrow;
                bq[j] = *(const s16x8*)(&Bls[n * 64 + (((quad + 4 * ks) ^ (n & 7)) * 8)]);
            }
#pragma unroll
            for (int i = 0; i < 4; i++)
#pragma unroll
                for (int j = 0; j < 4; j++)
                    acc[i][j] = __builtin_amdgcn_mfma_f32_16x16x32_bf16(af[i], bq[j], acc[i][j], 0, 0, 0);
        }
    }

    // epilogue: C/D layout col=lane&15, row=quad*4+reg
    const int lcol = lane & 15;
    float bv[4];
#pragma unroll
    for (int j = 0; j < 4; j++) bv[j] = bias[e * DD + wn + j * 16 + lcol];
#pragma unroll
    for (int i = 0; i < 4; i++) {
#pragma unroll
        for (int reg = 0; reg < 4; reg++) {
            int r = i * 16 + quad * 4 + reg;
            if (r < rows_valid) {
                int t = token_index[base + r];
                float* yr = y + (size_t)t * DD + wn + lcol;
#pragma unroll
                for (int j = 0; j < 4; j++)
                    yr[j * 16] = acc[i][j][reg] + bv[j];
            }
        }
    }
}

// ---------------- host ----------------

extern "C" void kernel_launch(void* const* d_in, const int* in_sizes, int n_in,
                              void* d_out, int out_size, void* d_ws, size_t ws_size,
                              hipStream_t stream) {
    const int*   z = (const int*)d_in[0];
    const float* x = (const float*)d_in[1];
    const float* W = (const float*)d_in[2];
    const float* b = (const float*)d_in[3];
    const int T = in_sizes[0];                 // 65536

    float* zout = (float*)d_out;               // [T] float(z)
    float* y    = (float*)d_out + T;           // [T][512]

    char* ws = (char*)d_ws;
    int*  counts      = (int*)ws;                        // 8 ints @ 0
    int*  cursors     = (int*)(ws + 64);                 // 8 ints
    int4* table       = (int4*)(ws + 256);               // <=1040 entries (16640 B)
    int*  token_index = (int*)(ws + 17408);              // T ints (ends 279552)
    unsigned short* Wt = (unsigned short*)(ws + 279552); // 4 MiB   (ends 4473856)

    const int max_tiles = T / BM + NEXP;       // 1032

    hipMemsetAsync(ws, 0, 64, stream);
    hist_kernel<<<(T + 255) / 256, 256, 0, stream>>>(z, counts, T);
    convw_kernel<<<dim3(DD / 32, DD / 32, NEXP), 256, 0, stream>>>(W, Wt);
    scan_kernel<<<1, 256, 0, stream>>>(counts, cursors, table, max_tiles);
    scatter_kernel<<<(T + 255) / 256, 256, 0, stream>>>(z, cursors, token_index, zout, T);
    gemm3_kernel<<<dim3(max_tiles), 512, 0, stream>>>(x, Wt, b, token_index, table, y);
}